// Round 2
// baseline (552.565 us; speedup 1.0000x reference)
//
#include <hip/hip_runtime.h>
#include <hip/hip_bf16.h>

// CausalMLA: B=2, L=2048, D=2048, H=16, HD=128, LD=32.
// Dtype-agnostic: on-device detector decides if d_in is bf16 or fp32; all inputs
// are normalized to bf16 workspace buffers, pipeline runs in bf16/MFMA, final
// store is bf16 or fp32 per flag.

#define Bsz 2
#define Lseq 2048
#define Dmod 2048
#define Hn 16
#define HDim 128
#define LDim 32

typedef __bf16 bf16x8 __attribute__((ext_vector_type(8)));
typedef float f32x4 __attribute__((ext_vector_type(4)));
typedef __hip_bfloat16 bf16;

// ---- small-constants area layout (bf16 element offsets inside `small`) ----
#define SM_COS 0
#define SM_SIN 131072
#define SM_WC 262144     // Wqc|Wkc|Wvc 3*4096
#define SM_BC 274432     // bqc|bkc|bvc 3*32
#define SM_WD 274528     // 4096
#define SM_BD 278624     // 128
#define SM_BO 278752     // 2048
#define SM_BQKV 280800   // bq|bk|bv 3*2048
#define SM_TOT 286944

// ---------------- dtype detector: 1 wave scans x's first 256 ushorts ----------------
__global__ void detect_dtype(const ushort* __restrict__ x, int* __restrict__ flag) {
  int t = threadIdx.x;  // 64 threads
  int bad = 0;
  for (int k = 0; k < 4; ++k) {
    ushort u = x[t * 4 + k];
    int ex = (u >> 7) & 0xFF;  // bf16 exponent field
    if (ex >= 0xC0) bad = 1;   // |v| >= 2^65: impossible for real bf16 activations
  }
  unsigned long long b = __ballot(bad);
  if (t == 0) *flag = (b != 0ULL) ? 1 : 0;  // 1 = inputs are fp32
}

__device__ inline void conv8(const void* src, size_t so, bf16* dst, size_t dof, int f32) {
  if (f32) {
    const float* s = (const float*)src + so;
    bf16 tmp[8] __attribute__((aligned(16)));
    for (int j = 0; j < 8; ++j) tmp[j] = __float2bfloat16(s[j]);
    *(uint4*)&dst[dof] = *(uint4*)tmp;
  } else {
    *(uint4*)&dst[dof] = *(const uint4*)((const ushort*)src + so);
  }
}

// ---------------- convert x (8388608 elements) ----------------
__global__ __launch_bounds__(256) void conv_x(const void* __restrict__ xs,
                                              bf16* __restrict__ xd,
                                              const int* __restrict__ flagp) {
  int f32 = *flagp;
  size_t e = ((size_t)blockIdx.x * 256 + threadIdx.x) * 8;  // grid 4096
  conv8(xs, e, xd, e, f32);
}

// ---------------- convert all small tensors into `small` area ----------------
__global__ __launch_bounds__(256) void conv_small(
    const void* cosS, const void* sinS, const void* WqcS, const void* WkcS,
    const void* WvcS, const void* bqcS, const void* bkcS, const void* bvcS,
    const void* WdS, const void* bdS, const void* boS, const void* bqS,
    const void* bkS, const void* bvS, bf16* __restrict__ dst,
    const int* __restrict__ flagp) {
  int f32 = *flagp;
  size_t e = ((size_t)blockIdx.x * 256 + threadIdx.x) * 8;
  if (e >= SM_TOT) return;
  const void* src;
  size_t so;
  if (e < SM_SIN) { src = cosS; so = e - SM_COS; }
  else if (e < SM_WC) { src = sinS; so = e - SM_SIN; }
  else if (e < SM_BC) { size_t r = e - SM_WC; src = (r < 4096) ? WqcS : (r < 8192) ? WkcS : WvcS; so = r & 4095; }
  else if (e < SM_WD) { size_t r = e - SM_BC; src = (r < 32) ? bqcS : (r < 64) ? bkcS : bvcS; so = r & 31; }
  else if (e < SM_BD) { src = WdS; so = e - SM_WD; }
  else if (e < SM_BO) { src = bdS; so = e - SM_BD; }
  else if (e < SM_BQKV) { src = boS; so = e - SM_BO; }
  else { size_t r = e - SM_BQKV; src = (r < 2048) ? bqS : (r < 4096) ? bkS : bvS; so = r & 2047; }
  conv8(src, so, dst, e, f32);
}

// ---------------- weight transpose (dtype-aware): Wt[n][k] = W[k][n] ----------------
__global__ __launch_bounds__(256) void transpose_any(const void* __restrict__ W,
                                                     bf16* __restrict__ Wt,
                                                     const int* __restrict__ flagp) {
  __shared__ float tile[64][65];
  int f32 = *flagp;
  int n0 = blockIdx.x * 64, k0 = blockIdx.y * 64;
  int t = threadIdx.x;
  int x = (t & 7) * 8, y = t >> 3;  // y in [0,32)
  for (int p = 0; p < 2; ++p) {
    int r = y + p * 32;
    if (f32) {
      const float* src = (const float*)W + (size_t)(k0 + r) * 2048 + n0 + x;
      float4 a = *(const float4*)src;
      float4 b2 = *(const float4*)(src + 4);
      tile[r][x + 0] = a.x; tile[r][x + 1] = a.y; tile[r][x + 2] = a.z; tile[r][x + 3] = a.w;
      tile[r][x + 4] = b2.x; tile[r][x + 5] = b2.y; tile[r][x + 6] = b2.z; tile[r][x + 7] = b2.w;
    } else {
      const ushort* src = (const ushort*)W + (size_t)(k0 + r) * 2048 + n0 + x;
      uint4 u = *(const uint4*)src;
      bf16* e = (bf16*)&u;
      for (int j = 0; j < 8; ++j) tile[r][x + j] = __bfloat162float(e[j]);
    }
  }
  __syncthreads();
  for (int p = 0; p < 2; ++p) {
    int n = y + p * 32;
    bf16 tmp[8] __attribute__((aligned(16)));
    for (int j = 0; j < 8; ++j) tmp[j] = __float2bfloat16(tile[x + j][n]);
    *(uint4*)&Wt[(size_t)(n0 + n) * 2048 + k0 + x] = *(uint4*)tmp;
  }
}

// ---------------- MFMA GEMM: C = A @ Bt^T + bias (bf16 out) ----------------
__global__ __launch_bounds__(256) void gemm_bias(const bf16* __restrict__ A,
                                                 const bf16* __restrict__ Bt,
                                                 const bf16* __restrict__ bias,
                                                 bf16* __restrict__ C,
                                                 int M, int N, int K) {
  __shared__ bf16 lA[128 * 32];
  __shared__ bf16 lB[128 * 32];
  int bm = blockIdx.y, bn = blockIdx.x;
  int t = threadIdx.x;
  int lane = t & 63, w = t >> 6;
  int wm = (w >> 1) * 64, wn = (w & 1) * 64;
  int qd = lane >> 4, ln = lane & 15;

  f32x4 acc[4][4] = {};
  const bf16* Ab = A + (size_t)(bm * 128) * K;
  const bf16* Bb = Bt + (size_t)(bn * 128) * K;

  for (int kt = 0; kt < K; kt += 32) {
    for (int p = 0; p < 2; ++p) {
      int slot = t + p * 256;
      int r = slot >> 2, c = (slot & 3) * 8;
      *(uint4*)&lA[r * 32 + c] = *(const uint4*)&Ab[(size_t)r * K + kt + c];
      *(uint4*)&lB[r * 32 + c] = *(const uint4*)&Bb[(size_t)r * K + kt + c];
    }
    __syncthreads();
    bf16x8 af[4], bfr[4];
    for (int i = 0; i < 4; ++i) af[i] = *(bf16x8*)&lA[(wm + i * 16 + ln) * 32 + qd * 8];
    for (int j = 0; j < 4; ++j) bfr[j] = *(bf16x8*)&lB[(wn + j * 16 + ln) * 32 + qd * 8];
    for (int i = 0; i < 4; ++i)
      for (int j = 0; j < 4; ++j)
        acc[i][j] = __builtin_amdgcn_mfma_f32_16x16x32_bf16(af[i], bfr[j], acc[i][j], 0, 0, 0);
    __syncthreads();
  }
  for (int i = 0; i < 4; ++i)
    for (int j = 0; j < 4; ++j) {
      int col = bn * 128 + wn + j * 16 + ln;
      float bv = __bfloat162float(bias[col]);
      for (int r = 0; r < 4; ++r) {
        int row = bm * 128 + wm + i * 16 + qd * 4 + r;
        C[(size_t)row * N + col] = __float2bfloat16(acc[i][j][r] + bv);
      }
    }
}

// ---------------- same GEMM, output dtype per flag (final projection) ----------------
__global__ __launch_bounds__(256) void gemm_bias_out(const bf16* __restrict__ A,
                                                     const bf16* __restrict__ Bt,
                                                     const bf16* __restrict__ bias,
                                                     void* __restrict__ C,
                                                     int M, int N, int K,
                                                     const int* __restrict__ flagp) {
  __shared__ bf16 lA[128 * 32];
  __shared__ bf16 lB[128 * 32];
  int f32out = *flagp;
  int bm = blockIdx.y, bn = blockIdx.x;
  int t = threadIdx.x;
  int lane = t & 63, w = t >> 6;
  int wm = (w >> 1) * 64, wn = (w & 1) * 64;
  int qd = lane >> 4, ln = lane & 15;

  f32x4 acc[4][4] = {};
  const bf16* Ab = A + (size_t)(bm * 128) * K;
  const bf16* Bb = Bt + (size_t)(bn * 128) * K;

  for (int kt = 0; kt < K; kt += 32) {
    for (int p = 0; p < 2; ++p) {
      int slot = t + p * 256;
      int r = slot >> 2, c = (slot & 3) * 8;
      *(uint4*)&lA[r * 32 + c] = *(const uint4*)&Ab[(size_t)r * K + kt + c];
      *(uint4*)&lB[r * 32 + c] = *(const uint4*)&Bb[(size_t)r * K + kt + c];
    }
    __syncthreads();
    bf16x8 af[4], bfr[4];
    for (int i = 0; i < 4; ++i) af[i] = *(bf16x8*)&lA[(wm + i * 16 + ln) * 32 + qd * 8];
    for (int j = 0; j < 4; ++j) bfr[j] = *(bf16x8*)&lB[(wn + j * 16 + ln) * 32 + qd * 8];
    for (int i = 0; i < 4; ++i)
      for (int j = 0; j < 4; ++j)
        acc[i][j] = __builtin_amdgcn_mfma_f32_16x16x32_bf16(af[i], bfr[j], acc[i][j], 0, 0, 0);
    __syncthreads();
  }
  for (int i = 0; i < 4; ++i)
    for (int j = 0; j < 4; ++j) {
      int col = bn * 128 + wn + j * 16 + ln;
      float bv = __bfloat162float(bias[col]);
      for (int r = 0; r < 4; ++r) {
        int row = bm * 128 + wm + i * 16 + qd * 4 + r;
        float v = acc[i][j][r] + bv;
        if (f32out) ((float*)C)[(size_t)row * N + col] = v;
        else ((bf16*)C)[(size_t)row * N + col] = __float2bfloat16(v);
      }
    }
}

// ---------------- RoPE + compression (q,k staged+RoPE'd in LDS; v from global) ----------------
__global__ __launch_bounds__(256) void rope_compress(const bf16* __restrict__ QKV,
                                                     const bf16* __restrict__ small,
                                                     bf16* __restrict__ qc,
                                                     bf16* __restrict__ kc,
                                                     bf16* __restrict__ vcT) {
  __shared__ bf16 rows[64][256];   // q(128)|k(128), RoPE applied
  __shared__ bf16 wsh[3 * 128 * 32];
  __shared__ float biasf[96];
  const bf16* cosb = small + SM_COS;
  const bf16* sinb = small + SM_SIN;
  const bf16* wc3 = small + SM_WC;
  const bf16* bc3 = small + SM_BC;
  int t = threadIdx.x, blk = blockIdx.x;
  int lt = blk & 31, bh = blk >> 5, h = bh & 15, b = bh >> 4, l0 = lt * 64;

  for (int s = t; s < 1536; s += 256) *(uint4*)&wsh[s * 8] = *(const uint4*)&wc3[s * 8];
  if (t < 96) biasf[t] = __bfloat162float(bc3[t]);
  for (int s = t; s < 2048; s += 256) {
    int r = s >> 5, c = s & 31, reg = c >> 4, coff = c & 15;
    int l = l0 + r;
    size_t gidx = (size_t)(b * Lseq + l) * 6144 + reg * 2048 + h * 128 + coff * 8;
    uint4 u = *(const uint4*)&QKV[gidx];
    bf16* e8 = (bf16*)&u;
    int pbase = coff * 4;
    for (int j = 0; j < 4; ++j) {
      float cv = __bfloat162float(cosb[l * 64 + pbase + j]);
      float sv = __bfloat162float(sinb[l * 64 + pbase + j]);
      float ev = __bfloat162float(e8[2 * j]);
      float ov = __bfloat162float(e8[2 * j + 1]);
      e8[2 * j] = __float2bfloat16(ev * cv - ov * sv);
      e8[2 * j + 1] = __float2bfloat16(ev * sv + ov * cv);
    }
    *(uint4*)&rows[r][c * 8] = u;
  }
  __syncthreads();

  int r = t >> 2, eo = (t & 3) * 8;
  int l = l0 + r;
  size_t orow = (size_t)bh * Lseq + l;
  for (int reg = 0; reg < 2; ++reg) {
    float acc[8];
    for (int j = 0; j < 8; ++j) acc[j] = biasf[reg * 32 + eo + j];
    const bf16* rp = &rows[r][reg * 128];
    const bf16* wp = &wsh[reg * 4096];
    for (int d = 0; d < 128; ++d) {
      float xv = __bfloat162float(rp[d]);
      uint4 wu = *(uint4*)&wp[d * 32 + eo];
      bf16* w8 = (bf16*)&wu;
      for (int j = 0; j < 8; ++j) acc[j] += xv * __bfloat162float(w8[j]);
    }
    bf16 outv[8] __attribute__((aligned(16)));
    for (int j = 0; j < 8; ++j) outv[j] = __float2bfloat16(acc[j]);
    if (reg == 0) *(uint4*)&qc[orow * 32 + eo] = *(uint4*)outv;
    else *(uint4*)&kc[orow * 32 + eo] = *(uint4*)outv;
  }
  {
    float acc[8];
    for (int j = 0; j < 8; ++j) acc[j] = biasf[64 + eo + j];
    const bf16* vg = &QKV[(size_t)(b * Lseq + l) * 6144 + 4096 + h * 128];
    const bf16* wp = &wsh[2 * 4096];
    for (int dc = 0; dc < 16; ++dc) {
      uint4 vv = *(const uint4*)&vg[dc * 8];
      bf16* v8 = (bf16*)&vv;
      for (int jj = 0; jj < 8; ++jj) {
        float xv = __bfloat162float(v8[jj]);
        uint4 wu = *(uint4*)&wp[(dc * 8 + jj) * 32 + eo];
        bf16* w8 = (bf16*)&wu;
        for (int j = 0; j < 8; ++j) acc[j] += xv * __bfloat162float(w8[j]);
      }
    }
    bf16 outv[8];
    for (int j = 0; j < 8; ++j) outv[j] = __float2bfloat16(acc[j]);
    for (int j = 0; j < 8; ++j) vcT[((size_t)bh * 32 + eo + j) * Lseq + l] = outv[j];
  }
}

// ---------------- flash attention over compressed dim (LD=32), causal ----------------
__global__ __launch_bounds__(256) void flash32(const bf16* __restrict__ qc,
                                               const bf16* __restrict__ kc,
                                               const bf16* __restrict__ vcT,
                                               bf16* __restrict__ attn) {
  __shared__ bf16 pbuf[4][16 * 32];
  int t = threadIdx.x;
  int lane = t & 63, w = t >> 6;
  int qd = lane >> 4, ln = lane & 15;
  int blk = blockIdx.x;
  int lt = blk & 31;
  int bh = blk >> 5;
  int q0 = lt * 64 + w * 16;

  bf16x8 qf = *(const bf16x8*)&qc[((size_t)bh * Lseq + q0 + ln) * 32 + qd * 8];

  f32x4 o0 = {}, o1 = {};
  float m[4], lsum[4];
  for (int r = 0; r < 4; ++r) { m[r] = -1e30f; lsum[r] = 0.f; }
  const float scale = 0.17677669529663687f;  // 1/sqrt(32)

  int nkt = (q0 + 16 + 31) >> 5;
  bf16* pb = pbuf[w];
  for (int kt = 0; kt < nkt; ++kt) {
    int k0 = kt * 32;
    bf16x8 kf0 = *(const bf16x8*)&kc[((size_t)bh * Lseq + k0 + ln) * 32 + qd * 8];
    bf16x8 kf1 = *(const bf16x8*)&kc[((size_t)bh * Lseq + k0 + 16 + ln) * 32 + qd * 8];
    f32x4 s0 = {}, s1 = {};
    s0 = __builtin_amdgcn_mfma_f32_16x16x32_bf16(qf, kf0, s0, 0, 0, 0);
    s1 = __builtin_amdgcn_mfma_f32_16x16x32_bf16(qf, kf1, s1, 0, 0, 0);
    float sv0[4], sv1[4], alpha[4];
    for (int r = 0; r < 4; ++r) {
      int qrow = q0 + qd * 4 + r;
      sv0[r] = (k0 + ln <= qrow) ? s0[r] * scale : -1e30f;
      sv1[r] = (k0 + 16 + ln <= qrow) ? s1[r] * scale : -1e30f;
    }
    for (int r = 0; r < 4; ++r) {
      float mx = fmaxf(sv0[r], sv1[r]);
      for (int off = 1; off < 16; off <<= 1) mx = fmaxf(mx, __shfl_xor(mx, off, 64));
      float mn = fmaxf(m[r], mx);
      alpha[r] = __expf(m[r] - mn);
      m[r] = mn;
      sv0[r] = __expf(sv0[r] - mn);
      sv1[r] = __expf(sv1[r] - mn);
      float rs = sv0[r] + sv1[r];
      for (int off = 1; off < 16; off <<= 1) rs += __shfl_xor(rs, off, 64);
      lsum[r] = lsum[r] * alpha[r] + rs;
      o0[r] *= alpha[r];
      o1[r] *= alpha[r];
    }
    for (int r = 0; r < 4; ++r) {
      pb[(qd * 4 + r) * 32 + ln] = __float2bfloat16(sv0[r]);
      pb[(qd * 4 + r) * 32 + 16 + ln] = __float2bfloat16(sv1[r]);
    }
    asm volatile("s_waitcnt lgkmcnt(0)" ::: "memory");
    bf16x8 pf = *(bf16x8*)&pb[ln * 32 + qd * 8];
    bf16x8 vf0 = *(const bf16x8*)&vcT[((size_t)bh * 32 + ln) * Lseq + k0 + qd * 8];
    bf16x8 vf1 = *(const bf16x8*)&vcT[((size_t)bh * 32 + 16 + ln) * Lseq + k0 + qd * 8];
    o0 = __builtin_amdgcn_mfma_f32_16x16x32_bf16(pf, vf0, o0, 0, 0, 0);
    o1 = __builtin_amdgcn_mfma_f32_16x16x32_bf16(pf, vf1, o1, 0, 0, 0);
  }
  for (int r = 0; r < 4; ++r) {
    float inv = 1.0f / lsum[r];
    size_t row = (size_t)bh * Lseq + q0 + qd * 4 + r;
    attn[row * 32 + ln] = __float2bfloat16(o0[r] * inv);
    attn[row * 32 + 16 + ln] = __float2bfloat16(o1[r] * inv);
  }
}

// ---------------- decompress: y[b,l,h*128+o] = attn[bh,l,:] @ Wd + bd ----------------
__global__ __launch_bounds__(256) void decompress(const bf16* __restrict__ attn,
                                                  const bf16* __restrict__ Wd,
                                                  const bf16* __restrict__ bd,
                                                  bf16* __restrict__ y) {
  __shared__ float wdl[32][128];
  __shared__ float arow[16][32];
  int t = threadIdx.x;
  for (int s = t; s < 4096; s += 256) wdl[s >> 7][s & 127] = __bfloat162float(Wd[s]);
  int row0 = blockIdx.x * 16;
  for (int s = t; s < 512; s += 256)
    arow[s >> 5][s & 31] = __bfloat162float(attn[(size_t)(row0 + (s >> 5)) * 32 + (s & 31)]);
  __syncthreads();
  int o = t & 127, rr = t >> 7;
  float wreg[32];
  for (int e = 0; e < 32; ++e) wreg[e] = wdl[e][o];
  float bv = __bfloat162float(bd[o]);
  for (int p = 0; p < 8; ++p) {
    int r = rr + p * 2;
    float acc = bv;
    for (int e = 0; e < 32; ++e) acc += arow[r][e] * wreg[e];
    int grow = row0 + r;  // (b*H + h)*L + l
    int b = grow >> 15, h = (grow >> 11) & 15, l = grow & 2047;
    y[((size_t)(b * Lseq + l)) * Dmod + h * 128 + o] = __float2bfloat16(acc);
  }
}

extern "C" void kernel_launch(void* const* d_in, const int* in_sizes, int n_in,
                              void* d_out, int out_size, void* d_ws, size_t ws_size,
                              hipStream_t stream) {
  const void* x = d_in[0];
  const void* cosS = d_in[1];
  const void* sinS = d_in[2];
  const void* Wq = d_in[3];
  const void* bq = d_in[4];
  const void* Wk = d_in[5];
  const void* bk = d_in[6];
  const void* Wv = d_in[7];
  const void* bv = d_in[8];
  const void* Wqc = d_in[9];
  const void* bqc = d_in[10];
  const void* Wkc = d_in[11];
  const void* bkc = d_in[12];
  const void* Wvc = d_in[13];
  const void* bvc = d_in[14];
  const void* Wd = d_in[15];
  const void* bd = d_in[16];
  const void* Wo = d_in[17];
  const void* bo = d_in[18];

  char* ws = (char*)d_ws;
  size_t off = 0;
  auto alloc = [&](size_t bytes) {
    char* p = ws + off;
    off += (bytes + 255) & ~(size_t)255;
    return p;
  };
  int* flag = (int*)alloc(256);
  bf16* small = (bf16*)alloc((size_t)SM_TOT * 2);
  bf16* xb = (bf16*)alloc((size_t)4096 * 2048 * 2);
  bf16* WtQKV = (bf16*)alloc((size_t)6144 * 2048 * 2);
  bf16* WtO = (bf16*)alloc((size_t)2048 * 2048 * 2);
  bf16* QKV = (bf16*)alloc((size_t)4096 * 6144 * 2);
  bf16* qcW = (bf16*)alloc((size_t)65536 * 32 * 2);
  bf16* kcW = (bf16*)alloc((size_t)65536 * 32 * 2);
  bf16* vcTW = (bf16*)alloc((size_t)65536 * 32 * 2);
  bf16* attnW = (bf16*)alloc((size_t)65536 * 32 * 2);
  bf16* yW = (bf16*)alloc((size_t)4096 * 2048 * 2);

  dim3 tb(256);
  detect_dtype<<<1, 64, 0, stream>>>((const ushort*)x, flag);
  conv_x<<<4096, tb, 0, stream>>>(x, xb, flag);
  conv_small<<<141, tb, 0, stream>>>(cosS, sinS, Wqc, Wkc, Wvc, bqc, bkc, bvc, Wd, bd,
                                     bo, bq, bk, bv, small, flag);
  transpose_any<<<dim3(32, 32), tb, 0, stream>>>(Wq, WtQKV, flag);
  transpose_any<<<dim3(32, 32), tb, 0, stream>>>(Wk, WtQKV + (size_t)2048 * 2048, flag);
  transpose_any<<<dim3(32, 32), tb, 0, stream>>>(Wv, WtQKV + (size_t)2 * 2048 * 2048, flag);
  transpose_any<<<dim3(32, 32), tb, 0, stream>>>(Wo, WtO, flag);
  gemm_bias<<<dim3(48, 32), tb, 0, stream>>>(xb, WtQKV, small + SM_BQKV, QKV, 4096, 6144, 2048);
  rope_compress<<<1024, tb, 0, stream>>>(QKV, small, qcW, kcW, vcTW);
  flash32<<<1024, tb, 0, stream>>>(qcW, kcW, vcTW, attnW);
  decompress<<<4096, tb, 0, stream>>>(attnW, small + SM_WD, small + SM_BD, yW);
  gemm_bias_out<<<dim3(16, 32), tb, 0, stream>>>(yW, WtO, small + SM_BO, d_out, 4096, 2048,
                                                 2048, flag);
}

// Round 3
// 529.579 us; speedup vs baseline: 1.0434x; 1.0434x over previous
//
#include <hip/hip_runtime.h>
#include <hip/hip_bf16.h>

// CausalMLA: B=2, L=2048, D=2048, H=16, HD=128, LD=32. Inputs fp32 or bf16
// (runtime-detected); pipeline runs bf16/MFMA; output dtype follows input.

#define Bsz 2
#define Lseq 2048
#define Dmod 2048
#define Hn 16
#define HDim 128
#define LDim 32

typedef __bf16 bf16x8 __attribute__((ext_vector_type(8)));
typedef float f32x4 __attribute__((ext_vector_type(4)));
typedef __hip_bfloat16 bf16;

#define GLDS16(g, l)                                                    \
  __builtin_amdgcn_global_load_lds(                                     \
      (const __attribute__((address_space(1))) unsigned int*)(g),       \
      (__attribute__((address_space(3))) unsigned int*)(l), 16, 0, 0)

// ---- small-constants area layout (bf16 element offsets inside `small`) ----
#define SM_COS 0
#define SM_SIN 131072
#define SM_WC 262144     // Wqc|Wkc|Wvc 3*4096
#define SM_BC 274432     // bqc|bkc|bvc 3*32
#define SM_WD 274528     // 4096
#define SM_BD 278624     // 128
#define SM_BO 278752     // 2048
#define SM_BQKV 280800   // bq|bk|bv 3*2048
#define SM_TOT 286944

// ---------------- dtype detector ----------------
__global__ void detect_dtype(const ushort* __restrict__ x, int* __restrict__ flag) {
  int t = threadIdx.x;  // 64 threads
  int bad = 0;
  for (int k = 0; k < 4; ++k) {
    ushort u = x[t * 4 + k];
    int ex = (u >> 7) & 0xFF;
    if (ex >= 0xC0) bad = 1;
  }
  unsigned long long b = __ballot(bad);
  if (t == 0) *flag = (b != 0ULL) ? 1 : 0;  // 1 = inputs are fp32
}

__device__ inline void conv8(const void* src, size_t so, bf16* dst, size_t dof, int f32) {
  if (f32) {
    const float* s = (const float*)src + so;
    bf16 tmp[8] __attribute__((aligned(16)));
    for (int j = 0; j < 8; ++j) tmp[j] = __float2bfloat16(s[j]);
    *(uint4*)&dst[dof] = *(uint4*)tmp;
  } else {
    *(uint4*)&dst[dof] = *(const uint4*)((const ushort*)src + so);
  }
}

__global__ __launch_bounds__(256) void conv_x(const void* __restrict__ xs,
                                              bf16* __restrict__ xd,
                                              const int* __restrict__ flagp) {
  int f32 = *flagp;
  size_t e = ((size_t)blockIdx.x * 256 + threadIdx.x) * 8;  // grid 4096
  conv8(xs, e, xd, e, f32);
}

__global__ __launch_bounds__(256) void conv_small(
    const void* cosS, const void* sinS, const void* WqcS, const void* WkcS,
    const void* WvcS, const void* bqcS, const void* bkcS, const void* bvcS,
    const void* WdS, const void* bdS, const void* boS, const void* bqS,
    const void* bkS, const void* bvS, bf16* __restrict__ dst,
    const int* __restrict__ flagp) {
  int f32 = *flagp;
  size_t e = ((size_t)blockIdx.x * 256 + threadIdx.x) * 8;
  if (e >= SM_TOT) return;
  const void* src;
  size_t so;
  if (e < SM_SIN) { src = cosS; so = e - SM_COS; }
  else if (e < SM_WC) { src = sinS; so = e - SM_SIN; }
  else if (e < SM_BC) { size_t r = e - SM_WC; src = (r < 4096) ? WqcS : (r < 8192) ? WkcS : WvcS; so = r & 4095; }
  else if (e < SM_WD) { size_t r = e - SM_BC; src = (r < 32) ? bqcS : (r < 64) ? bkcS : bvcS; so = r & 31; }
  else if (e < SM_BD) { src = WdS; so = e - SM_WD; }
  else if (e < SM_BO) { src = bdS; so = e - SM_BD; }
  else if (e < SM_BQKV) { src = boS; so = e - SM_BO; }
  else { size_t r = e - SM_BQKV; src = (r < 2048) ? bqS : (r < 4096) ? bkS : bvS; so = r & 2047; }
  conv8(src, so, dst, e, f32);
}

// ---------------- pre-transpose compression weights: WcT[reg][n][k], WdT[o][e] ----------------
__global__ __launch_bounds__(256) void prep_wt(const bf16* __restrict__ small,
                                               bf16* __restrict__ wctG,
                                               bf16* __restrict__ wdtG) {
  int t = blockIdx.x * 256 + threadIdx.x;  // grid 64 -> 16384
  if (t < 12288) {
    int reg = t >> 12, rem = t & 4095, n = rem >> 7, k = rem & 127;
    wctG[t] = small[SM_WC + reg * 4096 + k * 32 + n];
  } else if (t < 16384) {
    int i = t - 12288, o = i >> 5, e = i & 31;
    wdtG[i] = small[SM_WD + e * 128 + o];
  }
}

// ---------------- weight transpose (dtype-aware): Wt[n][k] = W[k][n] ----------------
__global__ __launch_bounds__(256) void transpose_any(const void* __restrict__ W,
                                                     bf16* __restrict__ Wt,
                                                     const int* __restrict__ flagp) {
  __shared__ float tile[64][65];
  int f32 = *flagp;
  int n0 = blockIdx.x * 64, k0 = blockIdx.y * 64;
  int t = threadIdx.x;
  int x = (t & 7) * 8, y = t >> 3;
  for (int p = 0; p < 2; ++p) {
    int r = y + p * 32;
    if (f32) {
      const float* src = (const float*)W + (size_t)(k0 + r) * 2048 + n0 + x;
      float4 a = *(const float4*)src;
      float4 b2 = *(const float4*)(src + 4);
      tile[r][x + 0] = a.x; tile[r][x + 1] = a.y; tile[r][x + 2] = a.z; tile[r][x + 3] = a.w;
      tile[r][x + 4] = b2.x; tile[r][x + 5] = b2.y; tile[r][x + 6] = b2.z; tile[r][x + 7] = b2.w;
    } else {
      const ushort* src = (const ushort*)W + (size_t)(k0 + r) * 2048 + n0 + x;
      uint4 u = *(const uint4*)src;
      bf16* e = (bf16*)&u;
      for (int j = 0; j < 8; ++j) tile[r][x + j] = __bfloat162float(e[j]);
    }
  }
  __syncthreads();
  for (int p = 0; p < 2; ++p) {
    int n = y + p * 32;
    bf16 tmp[8] __attribute__((aligned(16)));
    for (int j = 0; j < 8; ++j) tmp[j] = __float2bfloat16(tile[x + j][n]);
    *(uint4*)&Wt[(size_t)(n0 + n) * 2048 + k0 + x] = *(uint4*)tmp;
  }
}

// ---------------- MFMA GEMM with global_load_lds staging ----------------
__global__ __launch_bounds__(256) void gemm_bias(const bf16* __restrict__ A,
                                                 const bf16* __restrict__ Bt,
                                                 const bf16* __restrict__ bias,
                                                 bf16* __restrict__ C,
                                                 int M, int N, int K) {
  __shared__ bf16 lA[128 * 32];
  __shared__ bf16 lB[128 * 32];
  int bm = blockIdx.y, bn = blockIdx.x;
  int t = threadIdx.x;
  int lane = t & 63, w = t >> 6;
  int wm = (w >> 1) * 64, wn = (w & 1) * 64;
  int qd = lane >> 4, ln = lane & 15;

  f32x4 acc[4][4] = {};
  const bf16* Ab = A + (size_t)(bm * 128) * K;
  const bf16* Bb = Bt + (size_t)(bn * 128) * K;

  for (int kt = 0; kt < K; kt += 32) {
    for (int p = 0; p < 2; ++p) {
      int slot = t + p * 256;
      int r = slot >> 2, c = (slot & 3) * 8;
      GLDS16(&Ab[(size_t)r * K + kt + c], &lA[slot * 8]);
      GLDS16(&Bb[(size_t)r * K + kt + c], &lB[slot * 8]);
    }
    __syncthreads();
    bf16x8 af[4], bfr[4];
    for (int i = 0; i < 4; ++i) af[i] = *(bf16x8*)&lA[(wm + i * 16 + ln) * 32 + qd * 8];
    for (int j = 0; j < 4; ++j) bfr[j] = *(bf16x8*)&lB[(wn + j * 16 + ln) * 32 + qd * 8];
    for (int i = 0; i < 4; ++i)
      for (int j = 0; j < 4; ++j)
        acc[i][j] = __builtin_amdgcn_mfma_f32_16x16x32_bf16(af[i], bfr[j], acc[i][j], 0, 0, 0);
    __syncthreads();
  }
  for (int i = 0; i < 4; ++i)
    for (int j = 0; j < 4; ++j) {
      int col = bn * 128 + wn + j * 16 + ln;
      float bv = __bfloat162float(bias[col]);
      for (int r = 0; r < 4; ++r) {
        int row = bm * 128 + wm + i * 16 + qd * 4 + r;
        C[(size_t)row * N + col] = __float2bfloat16(acc[i][j][r] + bv);
      }
    }
}

__global__ __launch_bounds__(256) void gemm_bias_out(const bf16* __restrict__ A,
                                                     const bf16* __restrict__ Bt,
                                                     const bf16* __restrict__ bias,
                                                     void* __restrict__ C,
                                                     int M, int N, int K,
                                                     const int* __restrict__ flagp) {
  __shared__ bf16 lA[128 * 32];
  __shared__ bf16 lB[128 * 32];
  int f32out = *flagp;
  int bm = blockIdx.y, bn = blockIdx.x;
  int t = threadIdx.x;
  int lane = t & 63, w = t >> 6;
  int wm = (w >> 1) * 64, wn = (w & 1) * 64;
  int qd = lane >> 4, ln = lane & 15;

  f32x4 acc[4][4] = {};
  const bf16* Ab = A + (size_t)(bm * 128) * K;
  const bf16* Bb = Bt + (size_t)(bn * 128) * K;

  for (int kt = 0; kt < K; kt += 32) {
    for (int p = 0; p < 2; ++p) {
      int slot = t + p * 256;
      int r = slot >> 2, c = (slot & 3) * 8;
      GLDS16(&Ab[(size_t)r * K + kt + c], &lA[slot * 8]);
      GLDS16(&Bb[(size_t)r * K + kt + c], &lB[slot * 8]);
    }
    __syncthreads();
    bf16x8 af[4], bfr[4];
    for (int i = 0; i < 4; ++i) af[i] = *(bf16x8*)&lA[(wm + i * 16 + ln) * 32 + qd * 8];
    for (int j = 0; j < 4; ++j) bfr[j] = *(bf16x8*)&lB[(wn + j * 16 + ln) * 32 + qd * 8];
    for (int i = 0; i < 4; ++i)
      for (int j = 0; j < 4; ++j)
        acc[i][j] = __builtin_amdgcn_mfma_f32_16x16x32_bf16(af[i], bfr[j], acc[i][j], 0, 0, 0);
    __syncthreads();
  }
  for (int i = 0; i < 4; ++i)
    for (int j = 0; j < 4; ++j) {
      int col = bn * 128 + wn + j * 16 + ln;
      float bv = __bfloat162float(bias[col]);
      for (int r = 0; r < 4; ++r) {
        int row = bm * 128 + wm + i * 16 + qd * 4 + r;
        float v = acc[i][j][r] + bv;
        if (f32out) ((float*)C)[(size_t)row * N + col] = v;
        else ((bf16*)C)[(size_t)row * N + col] = __float2bfloat16(v);
      }
    }
}

// ---------------- RoPE + compression, MFMA, LDS-free ----------------
// Block: one (bh, 64-l tile); 4 waves x 16 rows. A-frags straight from QKV
// (RoPE in-register), B-frags from pre-transposed WcT (L2-hot).
__global__ __launch_bounds__(256) void rope_compress(const bf16* __restrict__ QKV,
                                                     const bf16* __restrict__ small,
                                                     const bf16* __restrict__ wctG,
                                                     bf16* __restrict__ qc,
                                                     bf16* __restrict__ kc,
                                                     bf16* __restrict__ vcT) {
  int t = threadIdx.x, blk = blockIdx.x;
  int lt = blk & 31, bh = blk >> 5, h = bh & 15, b = bh >> 4, l0 = lt * 64;
  int lane = t & 63, w = t >> 6, qd = lane >> 4, ln = lane & 15;
  int r0 = w * 16;
  int l = l0 + r0 + ln;  // this lane's A-row
  const bf16* cosb = small + SM_COS + l * 64;
  const bf16* sinb = small + SM_SIN + l * 64;
  size_t rowbase = (size_t)(b * Lseq + l) * 6144 + h * 128;

  for (int reg = 0; reg < 3; ++reg) {
    f32x4 acc0 = {}, acc1 = {};
    for (int kt = 0; kt < 4; ++kt) {
      uint4 u = *(const uint4*)&QKV[rowbase + reg * 2048 + kt * 32 + qd * 8];
      if (reg < 2) {
        bf16* e8 = (bf16*)&u;
        int pbase = kt * 16 + qd * 4;
        for (int j = 0; j < 4; ++j) {
          float cv = __bfloat162float(cosb[pbase + j]);
          float sv = __bfloat162float(sinb[pbase + j]);
          float ev = __bfloat162float(e8[2 * j]);
          float ov = __bfloat162float(e8[2 * j + 1]);
          e8[2 * j] = __float2bfloat16(ev * cv - ov * sv);
          e8[2 * j + 1] = __float2bfloat16(ev * sv + ov * cv);
        }
      }
      bf16x8 a = *(bf16x8*)&u;
      bf16x8 b0 = *(const bf16x8*)&wctG[reg * 4096 + ln * 128 + kt * 32 + qd * 8];
      bf16x8 b1 = *(const bf16x8*)&wctG[reg * 4096 + (16 + ln) * 128 + kt * 32 + qd * 8];
      acc0 = __builtin_amdgcn_mfma_f32_16x16x32_bf16(a, b0, acc0, 0, 0, 0);
      acc1 = __builtin_amdgcn_mfma_f32_16x16x32_bf16(a, b1, acc1, 0, 0, 0);
    }
    float bb0 = __bfloat162float(small[SM_BC + reg * 32 + ln]);
    float bb1 = __bfloat162float(small[SM_BC + reg * 32 + 16 + ln]);
    if (reg < 2) {
      bf16* dst = (reg == 0) ? qc : kc;
      for (int rr = 0; rr < 4; ++rr) {
        size_t o = (size_t)(bh * Lseq + l0 + r0 + qd * 4 + rr) * 32;
        dst[o + ln] = __float2bfloat16(acc0[rr] + bb0);
        dst[o + 16 + ln] = __float2bfloat16(acc1[rr] + bb1);
      }
    } else {
      bf16 p0[4] __attribute__((aligned(8))), p1[4] __attribute__((aligned(8)));
      for (int rr = 0; rr < 4; ++rr) {
        p0[rr] = __float2bfloat16(acc0[rr] + bb0);
        p1[rr] = __float2bfloat16(acc1[rr] + bb1);
      }
      int lbase = l0 + r0 + qd * 4;
      *(uint2*)&vcT[((size_t)bh * 32 + ln) * Lseq + lbase] = *(uint2*)p0;
      *(uint2*)&vcT[((size_t)bh * 32 + 16 + ln) * Lseq + lbase] = *(uint2*)p1;
    }
  }
}

// ---------------- flash attention (LD=32, causal) + fused decompress ----------------
__global__ __launch_bounds__(256) void flash32(const bf16* __restrict__ qc,
                                               const bf16* __restrict__ kc,
                                               const bf16* __restrict__ vcT,
                                               const bf16* __restrict__ small,
                                               const bf16* __restrict__ wdtG,
                                               bf16* __restrict__ y) {
  __shared__ bf16 pbuf[4][16 * 40];  // stride 40 breaks 8-way bank conflict
  int t = threadIdx.x;
  int lane = t & 63, w = t >> 6;
  int qd = lane >> 4, ln = lane & 15;
  int blk = blockIdx.x;
  int lt = blk & 31;
  int bh = blk >> 5, h = bh & 15, b = bh >> 4;
  int q0 = lt * 64 + w * 16;

  bf16x8 qf = *(const bf16x8*)&qc[((size_t)bh * Lseq + q0 + ln) * 32 + qd * 8];

  f32x4 o0 = {}, o1 = {};
  float m[4], lsum[4];
  for (int r = 0; r < 4; ++r) { m[r] = -1e30f; lsum[r] = 0.f; }
  const float scale = 0.17677669529663687f;  // 1/sqrt(32)

  int nkt = (q0 + 16 + 31) >> 5;
  bf16* pb = pbuf[w];
  for (int kt = 0; kt < nkt; ++kt) {
    int k0 = kt * 32;
    bf16x8 kf0 = *(const bf16x8*)&kc[((size_t)bh * Lseq + k0 + ln) * 32 + qd * 8];
    bf16x8 kf1 = *(const bf16x8*)&kc[((size_t)bh * Lseq + k0 + 16 + ln) * 32 + qd * 8];
    f32x4 s0 = {}, s1 = {};
    s0 = __builtin_amdgcn_mfma_f32_16x16x32_bf16(qf, kf0, s0, 0, 0, 0);
    s1 = __builtin_amdgcn_mfma_f32_16x16x32_bf16(qf, kf1, s1, 0, 0, 0);
    float sv0[4], sv1[4], alpha[4];
    for (int r = 0; r < 4; ++r) {
      int qrow = q0 + qd * 4 + r;
      sv0[r] = (k0 + ln <= qrow) ? s0[r] * scale : -1e30f;
      sv1[r] = (k0 + 16 + ln <= qrow) ? s1[r] * scale : -1e30f;
    }
    for (int r = 0; r < 4; ++r) {
      float mx = fmaxf(sv0[r], sv1[r]);
      for (int off = 1; off < 16; off <<= 1) mx = fmaxf(mx, __shfl_xor(mx, off, 64));
      float mn = fmaxf(m[r], mx);
      alpha[r] = __expf(m[r] - mn);
      m[r] = mn;
      sv0[r] = __expf(sv0[r] - mn);
      sv1[r] = __expf(sv1[r] - mn);
      float rs = sv0[r] + sv1[r];
      for (int off = 1; off < 16; off <<= 1) rs += __shfl_xor(rs, off, 64);
      lsum[r] = lsum[r] * alpha[r] + rs;
      o0[r] *= alpha[r];
      o1[r] *= alpha[r];
    }
    for (int r = 0; r < 4; ++r) {
      pb[(qd * 4 + r) * 40 + ln] = __float2bfloat16(sv0[r]);
      pb[(qd * 4 + r) * 40 + 16 + ln] = __float2bfloat16(sv1[r]);
    }
    asm volatile("s_waitcnt lgkmcnt(0)" ::: "memory");
    bf16x8 pf = *(bf16x8*)&pb[ln * 40 + qd * 8];
    bf16x8 vf0 = *(const bf16x8*)&vcT[((size_t)bh * 32 + ln) * Lseq + k0 + qd * 8];
    bf16x8 vf1 = *(const bf16x8*)&vcT[((size_t)bh * 32 + 16 + ln) * Lseq + k0 + qd * 8];
    o0 = __builtin_amdgcn_mfma_f32_16x16x32_bf16(pf, vf0, o0, 0, 0, 0);
    o1 = __builtin_amdgcn_mfma_f32_16x16x32_bf16(pf, vf1, o1, 0, 0, 0);
  }
  // epilogue: normalize, C-layout -> A-layout via LDS, then x WdT -> y
  for (int r = 0; r < 4; ++r) {
    float inv = 1.0f / lsum[r];
    pb[(qd * 4 + r) * 40 + ln] = __float2bfloat16(o0[r] * inv);
    pb[(qd * 4 + r) * 40 + 16 + ln] = __float2bfloat16(o1[r] * inv);
  }
  asm volatile("s_waitcnt lgkmcnt(0)" ::: "memory");
  bf16x8 pf = *(bf16x8*)&pb[ln * 40 + qd * 8];
  for (int nt = 0; nt < 8; ++nt) {
    bf16x8 bfr = *(const bf16x8*)&wdtG[(nt * 16 + ln) * 32 + qd * 8];
    f32x4 yacc = {};
    yacc = __builtin_amdgcn_mfma_f32_16x16x32_bf16(pf, bfr, yacc, 0, 0, 0);
    float bb = __bfloat162float(small[SM_BD + nt * 16 + ln]);
    for (int rr = 0; rr < 4; ++rr) {
      int l = q0 + qd * 4 + rr;
      y[(size_t)(b * Lseq + l) * Dmod + h * 128 + nt * 16 + ln] =
          __float2bfloat16(yacc[rr] + bb);
    }
  }
}

extern "C" void kernel_launch(void* const* d_in, const int* in_sizes, int n_in,
                              void* d_out, int out_size, void* d_ws, size_t ws_size,
                              hipStream_t stream) {
  const void* x = d_in[0];
  const void* cosS = d_in[1];
  const void* sinS = d_in[2];
  const void* Wq = d_in[3];
  const void* bq = d_in[4];
  const void* Wk = d_in[5];
  const void* bk = d_in[6];
  const void* Wv = d_in[7];
  const void* bv = d_in[8];
  const void* Wqc = d_in[9];
  const void* bqc = d_in[10];
  const void* Wkc = d_in[11];
  const void* bkc = d_in[12];
  const void* Wvc = d_in[13];
  const void* bvc = d_in[14];
  const void* Wd = d_in[15];
  const void* bd = d_in[16];
  const void* Wo = d_in[17];
  const void* bo = d_in[18];

  char* ws = (char*)d_ws;
  size_t off = 0;
  auto alloc = [&](size_t bytes) {
    char* p = ws + off;
    off += (bytes + 255) & ~(size_t)255;
    return p;
  };
  int* flag = (int*)alloc(256);
  bf16* small = (bf16*)alloc((size_t)SM_TOT * 2);
  bf16* wctG = (bf16*)alloc((size_t)12288 * 2);
  bf16* wdtG = (bf16*)alloc((size_t)4096 * 2);
  bf16* xb = (bf16*)alloc((size_t)4096 * 2048 * 2);
  bf16* WtQKV = (bf16*)alloc((size_t)6144 * 2048 * 2);
  bf16* WtO = (bf16*)alloc((size_t)2048 * 2048 * 2);
  bf16* QKV = (bf16*)alloc((size_t)4096 * 6144 * 2);
  bf16* qcW = (bf16*)alloc((size_t)65536 * 32 * 2);
  bf16* kcW = (bf16*)alloc((size_t)65536 * 32 * 2);
  bf16* vcTW = (bf16*)alloc((size_t)65536 * 32 * 2);
  bf16* yW = (bf16*)alloc((size_t)4096 * 2048 * 2);

  dim3 tb(256);
  detect_dtype<<<1, 64, 0, stream>>>((const ushort*)x, flag);
  conv_x<<<4096, tb, 0, stream>>>(x, xb, flag);
  conv_small<<<141, tb, 0, stream>>>(cosS, sinS, Wqc, Wkc, Wvc, bqc, bkc, bvc, Wd, bd,
                                     bo, bq, bk, bv, small, flag);
  prep_wt<<<64, tb, 0, stream>>>(small, wctG, wdtG);
  transpose_any<<<dim3(32, 32), tb, 0, stream>>>(Wq, WtQKV, flag);
  transpose_any<<<dim3(32, 32), tb, 0, stream>>>(Wk, WtQKV + (size_t)2048 * 2048, flag);
  transpose_any<<<dim3(32, 32), tb, 0, stream>>>(Wv, WtQKV + (size_t)2 * 2048 * 2048, flag);
  transpose_any<<<dim3(32, 32), tb, 0, stream>>>(Wo, WtO, flag);
  gemm_bias<<<dim3(48, 32), tb, 0, stream>>>(xb, WtQKV, small + SM_BQKV, QKV, 4096, 6144, 2048);
  rope_compress<<<1024, tb, 0, stream>>>(QKV, small, wctG, qcW, kcW, vcTW);
  flash32<<<1024, tb, 0, stream>>>(qcW, kcW, vcTW, small, wdtG, yW);
  gemm_bias_out<<<dim3(16, 32), tb, 0, stream>>>(yW, WtO, small + SM_BO, d_out, 4096, 2048,
                                                 2048, flag);
}

// Round 4
// 472.892 us; speedup vs baseline: 1.1685x; 1.1199x over previous
//
#include <hip/hip_runtime.h>
#include <hip/hip_bf16.h>

// CausalMLA: B=2, L=2048, D=2048, H=16, HD=128, LD=32. Inputs fp32 or bf16
// (runtime-detected); pipeline bf16/MFMA; output dtype follows input.
// R4: RoPE+compress fused into QKV-GEMM epilogue (each bn block = one (reg,head));
//     13 -> 7 dispatches.

#define Bsz 2
#define Lseq 2048
#define Dmod 2048
#define Hn 16
#define HDim 128
#define LDim 32

typedef __bf16 bf16x8 __attribute__((ext_vector_type(8)));
typedef float f32x4 __attribute__((ext_vector_type(4)));
typedef __hip_bfloat16 bf16;

#define GLDS16(g, l)                                                    \
  __builtin_amdgcn_global_load_lds(                                     \
      (const __attribute__((address_space(1))) unsigned int*)(g),       \
      (__attribute__((address_space(3))) unsigned int*)(l), 16, 0, 0)

// ---- small-constants area layout (bf16 element offsets inside `small`) ----
#define SM_COS 0
#define SM_SIN 131072
#define SM_WC 262144     // Wqc|Wkc|Wvc 3*4096 (unused downstream, kept cheap)
#define SM_BC 274432     // bqc|bkc|bvc 3*32
#define SM_WD 274528     // 4096 (unused downstream)
#define SM_BD 278624     // 128
#define SM_BO 278752     // 2048
#define SM_BQKV 280800   // bq|bk|bv 3*2048
#define SM_TOT 286944

// ---------------- dtype detector ----------------
__global__ void detect_dtype(const ushort* __restrict__ x, int* __restrict__ flag) {
  int t = threadIdx.x;  // 64 threads
  int bad = 0;
  for (int k = 0; k < 4; ++k) {
    ushort u = x[t * 4 + k];
    int ex = (u >> 7) & 0xFF;
    if (ex >= 0xC0) bad = 1;
  }
  unsigned long long b = __ballot(bad);
  if (t == 0) *flag = (b != 0ULL) ? 1 : 0;  // 1 = inputs are fp32
}

__device__ inline void conv8(const void* src, size_t so, bf16* dst, size_t dof, int f32) {
  if (f32) {
    const float* s = (const float*)src + so;
    bf16 tmp[8] __attribute__((aligned(16)));
    for (int j = 0; j < 8; ++j) tmp[j] = __float2bfloat16(s[j]);
    *(uint4*)&dst[dof] = *(uint4*)tmp;
  } else {
    *(uint4*)&dst[dof] = *(const uint4*)((const ushort*)src + so);
  }
}

__device__ inline float cv1(const void* s, size_t i, int f32) {
  return f32 ? ((const float*)s)[i] : __bfloat162float(((const bf16*)s)[i]);
}

__global__ __launch_bounds__(256) void conv_x(const void* __restrict__ xs,
                                              bf16* __restrict__ xd,
                                              const int* __restrict__ flagp) {
  int f32 = *flagp;
  size_t e = ((size_t)blockIdx.x * 256 + threadIdx.x) * 8;  // grid 4096
  conv8(xs, e, xd, e, f32);
}

// ---------------- prep: small-area conversion + wctG/wdtG, all from inputs ----------------
__global__ __launch_bounds__(256) void prep(
    const void* cosS, const void* sinS, const void* WqcS, const void* WkcS,
    const void* WvcS, const void* bqcS, const void* bkcS, const void* bvcS,
    const void* WdS, const void* bdS, const void* boS, const void* bqS,
    const void* bkS, const void* bvS, bf16* __restrict__ dst,
    bf16* __restrict__ wctG, bf16* __restrict__ wdtG,
    const int* __restrict__ flagp) {
  int f32 = *flagp;
  int tid = blockIdx.x * 256 + threadIdx.x;  // grid 160 -> 40960
  if (tid < SM_TOT / 8) {
    size_t e = (size_t)tid * 8;
    const void* src;
    size_t so;
    if (e < SM_SIN) { src = cosS; so = e - SM_COS; }
    else if (e < SM_WC) { src = sinS; so = e - SM_SIN; }
    else if (e < SM_BC) { size_t r = e - SM_WC; src = (r < 4096) ? WqcS : (r < 8192) ? WkcS : WvcS; so = r & 4095; }
    else if (e < SM_WD) { size_t r = e - SM_BC; src = (r < 32) ? bqcS : (r < 64) ? bkcS : bvcS; so = r & 31; }
    else if (e < SM_BD) { src = WdS; so = e - SM_WD; }
    else if (e < SM_BO) { src = bdS; so = e - SM_BD; }
    else if (e < SM_BQKV) { src = boS; so = e - SM_BO; }
    else { size_t r = e - SM_BQKV; src = (r < 2048) ? bqS : (r < 4096) ? bkS : bvS; so = r & 2047; }
    conv8(src, so, dst, e, f32);
  } else {
    int idx = tid - SM_TOT / 8;  // 0..5091
    for (int i = idx; i < 16384; i += 40960 - SM_TOT / 8) {
      if (i < 12288) {
        int reg = i >> 12, rem = i & 4095, n = rem >> 7, k = rem & 127;
        const void* src = (reg == 0) ? WqcS : (reg == 1) ? WkcS : WvcS;
        wctG[i] = __float2bfloat16(cv1(src, (size_t)k * 32 + n, f32));
      } else {
        int i2 = i - 12288, o = i2 >> 5, e = i2 & 31;
        wdtG[i2] = __float2bfloat16(cv1(WdS, (size_t)e * 128 + o, f32));
      }
    }
  }
}

// ---------------- 4 weight transposes in one kernel: Wt[n][k] = W[k][n] ----------------
__global__ __launch_bounds__(256) void transpose4(const void* __restrict__ WqS,
                                                  const void* __restrict__ WkS,
                                                  const void* __restrict__ WvS,
                                                  const void* __restrict__ WoS,
                                                  bf16* __restrict__ WtQKV,
                                                  bf16* __restrict__ WtO,
                                                  const int* __restrict__ flagp) {
  __shared__ float tile[64][65];
  int f32 = *flagp;
  int z = blockIdx.z;
  const void* W = (z == 0) ? WqS : (z == 1) ? WkS : (z == 2) ? WvS : WoS;
  bf16* Wt = (z == 3) ? WtO : (WtQKV + (size_t)z * 2048 * 2048);
  int n0 = blockIdx.x * 64, k0 = blockIdx.y * 64;
  int t = threadIdx.x;
  int x = (t & 7) * 8, y = t >> 3;
  for (int p = 0; p < 2; ++p) {
    int r = y + p * 32;
    if (f32) {
      const float* src = (const float*)W + (size_t)(k0 + r) * 2048 + n0 + x;
      float4 a = *(const float4*)src;
      float4 b2 = *(const float4*)(src + 4);
      tile[r][x + 0] = a.x; tile[r][x + 1] = a.y; tile[r][x + 2] = a.z; tile[r][x + 3] = a.w;
      tile[r][x + 4] = b2.x; tile[r][x + 5] = b2.y; tile[r][x + 6] = b2.z; tile[r][x + 7] = b2.w;
    } else {
      const ushort* src = (const ushort*)W + (size_t)(k0 + r) * 2048 + n0 + x;
      uint4 u = *(const uint4*)src;
      bf16* e = (bf16*)&u;
      for (int j = 0; j < 8; ++j) tile[r][x + j] = __bfloat162float(e[j]);
    }
  }
  __syncthreads();
  for (int p = 0; p < 2; ++p) {
    int n = y + p * 32;
    bf16 tmp[8] __attribute__((aligned(16)));
    for (int j = 0; j < 8; ++j) tmp[j] = __float2bfloat16(tile[x + j][n]);
    *(uint4*)&Wt[(size_t)(n0 + n) * 2048 + k0 + x] = *(uint4*)tmp;
  }
}

// ---------------- QKV GEMM + fused RoPE + compression ----------------
// Block = (bn = reg*16+h, bm = b*16 + ltile). K-loop: m97-style 128x128x32.
// Epilogue: acc(+bias) -> LDS tile (128 l x 128 hd), RoPE on A-frag read,
// 16 MFMAs vs wctG -> qc/kc/vcT directly. QKV never touches global.
#define ESTR 136  // epilogue LDS row stride (16B-aligned rows; low bank conflict)
__global__ __launch_bounds__(256) void gemm_qkv_compress(
    const bf16* __restrict__ A, const bf16* __restrict__ Bt,
    const bf16* __restrict__ small, const bf16* __restrict__ wctG,
    bf16* __restrict__ qc, bf16* __restrict__ kc, bf16* __restrict__ vcT) {
  __shared__ bf16 sh[128 * ESTR];  // 34816 B; first 16KB doubles as lA|lB
  bf16* lA = sh;
  bf16* lB = sh + 4096;
  const int K = 2048;
  int bm = blockIdx.y, bn = blockIdx.x;
  int reg = bn >> 4, h = bn & 15;
  int t = threadIdx.x;
  int lane = t & 63, w = t >> 6;
  int wm = (w >> 1) * 64, wn = (w & 1) * 64;
  int qd = lane >> 4, ln = lane & 15;

  f32x4 acc[4][4] = {};
  const bf16* Ab = A + (size_t)(bm * 128) * K;
  const bf16* Bb = Bt + (size_t)(bn * 128) * K;

  for (int kt = 0; kt < K; kt += 32) {
    for (int p = 0; p < 2; ++p) {
      int slot = t + p * 256;
      int r = slot >> 2, c = (slot & 3) * 8;
      GLDS16(&Ab[(size_t)r * K + kt + c], &lA[slot * 8]);
      GLDS16(&Bb[(size_t)r * K + kt + c], &lB[slot * 8]);
    }
    __syncthreads();
    bf16x8 af[4], bfr[4];
    for (int i = 0; i < 4; ++i) af[i] = *(bf16x8*)&lA[(wm + i * 16 + ln) * 32 + qd * 8];
    for (int j = 0; j < 4; ++j) bfr[j] = *(bf16x8*)&lB[(wn + j * 16 + ln) * 32 + qd * 8];
    for (int i = 0; i < 4; ++i)
      for (int j = 0; j < 4; ++j)
        acc[i][j] = __builtin_amdgcn_mfma_f32_16x16x32_bf16(af[i], bfr[j], acc[i][j], 0, 0, 0);
    __syncthreads();
  }

  // epilogue 1: acc + bias -> LDS tile (row = block-local l, col = head dim)
  for (int j = 0; j < 4; ++j) {
    int col = wn + j * 16 + ln;
    float bv = __bfloat162float(small[SM_BQKV + bn * 128 + col]);
    for (int i = 0; i < 4; ++i)
      for (int r = 0; r < 4; ++r)
        sh[(wm + i * 16 + qd * 4 + r) * ESTR + col] = __float2bfloat16(acc[i][j][r] + bv);
  }
  __syncthreads();

  // epilogue 2: compress 32 l-rows per wave (2 m-tiles x 2 n-tiles x 4 kt)
  int r0 = w * 32;
  int b = bm >> 4;
  int bh = b * Hn + h;
  bf16x8 bfr2[2][4];
  for (int nt = 0; nt < 2; ++nt)
    for (int kt = 0; kt < 4; ++kt)
      bfr2[nt][kt] = *(const bf16x8*)&wctG[reg * 4096 + (nt * 16 + ln) * 128 + kt * 32 + qd * 8];
  float bc[2];
  bc[0] = __bfloat162float(small[SM_BC + reg * 32 + ln]);
  bc[1] = __bfloat162float(small[SM_BC + reg * 32 + 16 + ln]);

  for (int mt = 0; mt < 2; ++mt) {
    int lb = r0 + mt * 16 + ln;               // block-local A-row
    int lg = (bm & 15) * 128 + lb;            // global l
    f32x4 c2[2] = {};
    for (int kt = 0; kt < 4; ++kt) {
      uint4 u = *(uint4*)&sh[lb * ESTR + kt * 32 + qd * 8];
      if (reg < 2) {
        bf16* e8 = (bf16*)&u;
        int pbase = kt * 16 + qd * 4;
        for (int j = 0; j < 4; ++j) {
          float cvv = __bfloat162float(small[SM_COS + (size_t)lg * 64 + pbase + j]);
          float svv = __bfloat162float(small[SM_SIN + (size_t)lg * 64 + pbase + j]);
          float ev = __bfloat162float(e8[2 * j]);
          float ov = __bfloat162float(e8[2 * j + 1]);
          e8[2 * j] = __float2bfloat16(ev * cvv - ov * svv);
          e8[2 * j + 1] = __float2bfloat16(ev * svv + ov * cvv);
        }
      }
      bf16x8 a = *(bf16x8*)&u;
      c2[0] = __builtin_amdgcn_mfma_f32_16x16x32_bf16(a, bfr2[0][kt], c2[0], 0, 0, 0);
      c2[1] = __builtin_amdgcn_mfma_f32_16x16x32_bf16(a, bfr2[1][kt], c2[1], 0, 0, 0);
    }
    // C-layout: row (l) = r0 + mt*16 + qd*4 + r, col (e) = nt*16 + ln
    int lgbase = (bm & 15) * 128 + r0 + mt * 16 + qd * 4;
    if (reg < 2) {
      bf16* dst = (reg == 0) ? qc : kc;
      for (int nt = 0; nt < 2; ++nt)
        for (int r = 0; r < 4; ++r)
          dst[((size_t)bh * Lseq + lgbase + r) * 32 + nt * 16 + ln] =
              __float2bfloat16(c2[nt][r] + bc[nt]);
    } else {
      for (int nt = 0; nt < 2; ++nt) {
        bf16 p4[4] __attribute__((aligned(8)));
        for (int r = 0; r < 4; ++r) p4[r] = __float2bfloat16(c2[nt][r] + bc[nt]);
        *(uint2*)&vcT[((size_t)bh * 32 + nt * 16 + ln) * Lseq + lgbase] = *(uint2*)p4;
      }
    }
  }
}

// ---------------- output GEMM: d_out = y @ WtO^T + bo, dtype per flag ----------------
__global__ __launch_bounds__(256) void gemm_bias_out(const bf16* __restrict__ A,
                                                     const bf16* __restrict__ Bt,
                                                     const bf16* __restrict__ bias,
                                                     void* __restrict__ C,
                                                     int M, int N, int K,
                                                     const int* __restrict__ flagp) {
  __shared__ bf16 lA[128 * 32];
  __shared__ bf16 lB[128 * 32];
  int f32out = *flagp;
  int bm = blockIdx.y, bn = blockIdx.x;
  int t = threadIdx.x;
  int lane = t & 63, w = t >> 6;
  int wm = (w >> 1) * 64, wn = (w & 1) * 64;
  int qd = lane >> 4, ln = lane & 15;

  f32x4 acc[4][4] = {};
  const bf16* Ab = A + (size_t)(bm * 128) * K;
  const bf16* Bb = Bt + (size_t)(bn * 128) * K;

  for (int kt = 0; kt < K; kt += 32) {
    for (int p = 0; p < 2; ++p) {
      int slot = t + p * 256;
      int r = slot >> 2, c = (slot & 3) * 8;
      GLDS16(&Ab[(size_t)r * K + kt + c], &lA[slot * 8]);
      GLDS16(&Bb[(size_t)r * K + kt + c], &lB[slot * 8]);
    }
    __syncthreads();
    bf16x8 af[4], bfr[4];
    for (int i = 0; i < 4; ++i) af[i] = *(bf16x8*)&lA[(wm + i * 16 + ln) * 32 + qd * 8];
    for (int j = 0; j < 4; ++j) bfr[j] = *(bf16x8*)&lB[(wn + j * 16 + ln) * 32 + qd * 8];
    for (int i = 0; i < 4; ++i)
      for (int j = 0; j < 4; ++j)
        acc[i][j] = __builtin_amdgcn_mfma_f32_16x16x32_bf16(af[i], bfr[j], acc[i][j], 0, 0, 0);
    __syncthreads();
  }
  for (int i = 0; i < 4; ++i)
    for (int j = 0; j < 4; ++j) {
      int col = bn * 128 + wn + j * 16 + ln;
      float bv = __bfloat162float(bias[col]);
      for (int r = 0; r < 4; ++r) {
        int row = bm * 128 + wm + i * 16 + qd * 4 + r;
        float v = acc[i][j][r] + bv;
        if (f32out) ((float*)C)[(size_t)row * N + col] = v;
        else ((bf16*)C)[(size_t)row * N + col] = __float2bfloat16(v);
      }
    }
}

// ---------------- flash attention (LD=32, causal) + fused decompress ----------------
__global__ __launch_bounds__(256) void flash32(const bf16* __restrict__ qc,
                                               const bf16* __restrict__ kc,
                                               const bf16* __restrict__ vcT,
                                               const bf16* __restrict__ small,
                                               const bf16* __restrict__ wdtG,
                                               bf16* __restrict__ y) {
  __shared__ bf16 pbuf[4][16 * 40];
  int t = threadIdx.x;
  int lane = t & 63, w = t >> 6;
  int qd = lane >> 4, ln = lane & 15;
  int blk = blockIdx.x;
  int lt = blk & 31;
  int bh = blk >> 5, h = bh & 15, b = bh >> 4;
  int q0 = lt * 64 + w * 16;

  bf16x8 qf = *(const bf16x8*)&qc[((size_t)bh * Lseq + q0 + ln) * 32 + qd * 8];

  f32x4 o0 = {}, o1 = {};
  float m[4], lsum[4];
  for (int r = 0; r < 4; ++r) { m[r] = -1e30f; lsum[r] = 0.f; }
  const float scale = 0.17677669529663687f;  // 1/sqrt(32)

  int nkt = (q0 + 16 + 31) >> 5;
  bf16* pb = pbuf[w];
  for (int kt = 0; kt < nkt; ++kt) {
    int k0 = kt * 32;
    bf16x8 kf0 = *(const bf16x8*)&kc[((size_t)bh * Lseq + k0 + ln) * 32 + qd * 8];
    bf16x8 kf1 = *(const bf16x8*)&kc[((size_t)bh * Lseq + k0 + 16 + ln) * 32 + qd * 8];
    f32x4 s0 = {}, s1 = {};
    s0 = __builtin_amdgcn_mfma_f32_16x16x32_bf16(qf, kf0, s0, 0, 0, 0);
    s1 = __builtin_amdgcn_mfma_f32_16x16x32_bf16(qf, kf1, s1, 0, 0, 0);
    float sv0[4], sv1[4], alpha[4];
    for (int r = 0; r < 4; ++r) {
      int qrow = q0 + qd * 4 + r;
      sv0[r] = (k0 + ln <= qrow) ? s0[r] * scale : -1e30f;
      sv1[r] = (k0 + 16 + ln <= qrow) ? s1[r] * scale : -1e30f;
    }
    for (int r = 0; r < 4; ++r) {
      float mx = fmaxf(sv0[r], sv1[r]);
      for (int off = 1; off < 16; off <<= 1) mx = fmaxf(mx, __shfl_xor(mx, off, 64));
      float mn = fmaxf(m[r], mx);
      alpha[r] = __expf(m[r] - mn);
      m[r] = mn;
      sv0[r] = __expf(sv0[r] - mn);
      sv1[r] = __expf(sv1[r] - mn);
      float rs = sv0[r] + sv1[r];
      for (int off = 1; off < 16; off <<= 1) rs += __shfl_xor(rs, off, 64);
      lsum[r] = lsum[r] * alpha[r] + rs;
      o0[r] *= alpha[r];
      o1[r] *= alpha[r];
    }
    for (int r = 0; r < 4; ++r) {
      pb[(qd * 4 + r) * 40 + ln] = __float2bfloat16(sv0[r]);
      pb[(qd * 4 + r) * 40 + 16 + ln] = __float2bfloat16(sv1[r]);
    }
    asm volatile("s_waitcnt lgkmcnt(0)" ::: "memory");
    bf16x8 pf = *(bf16x8*)&pb[ln * 40 + qd * 8];
    bf16x8 vf0 = *(const bf16x8*)&vcT[((size_t)bh * 32 + ln) * Lseq + k0 + qd * 8];
    bf16x8 vf1 = *(const bf16x8*)&vcT[((size_t)bh * 32 + 16 + ln) * Lseq + k0 + qd * 8];
    o0 = __builtin_amdgcn_mfma_f32_16x16x32_bf16(pf, vf0, o0, 0, 0, 0);
    o1 = __builtin_amdgcn_mfma_f32_16x16x32_bf16(pf, vf1, o1, 0, 0, 0);
  }
  // epilogue: normalize, C->A layout via LDS, x WdT -> y
  for (int r = 0; r < 4; ++r) {
    float inv = 1.0f / lsum[r];
    pb[(qd * 4 + r) * 40 + ln] = __float2bfloat16(o0[r] * inv);
    pb[(qd * 4 + r) * 40 + 16 + ln] = __float2bfloat16(o1[r] * inv);
  }
  asm volatile("s_waitcnt lgkmcnt(0)" ::: "memory");
  bf16x8 pf = *(bf16x8*)&pb[ln * 40 + qd * 8];
  for (int nt = 0; nt < 8; ++nt) {
    bf16x8 bfr = *(const bf16x8*)&wdtG[(nt * 16 + ln) * 32 + qd * 8];
    f32x4 yacc = {};
    yacc = __builtin_amdgcn_mfma_f32_16x16x32_bf16(pf, bfr, yacc, 0, 0, 0);
    float bb = __bfloat162float(small[SM_BD + nt * 16 + ln]);
    for (int rr = 0; rr < 4; ++rr) {
      int l = q0 + qd * 4 + rr;
      y[(size_t)(b * Lseq + l) * Dmod + h * 128 + nt * 16 + ln] =
          __float2bfloat16(yacc[rr] + bb);
    }
  }
}

extern "C" void kernel_launch(void* const* d_in, const int* in_sizes, int n_in,
                              void* d_out, int out_size, void* d_ws, size_t ws_size,
                              hipStream_t stream) {
  const void* x = d_in[0];
  const void* cosS = d_in[1];
  const void* sinS = d_in[2];
  const void* Wq = d_in[3];
  const void* bq = d_in[4];
  const void* Wk = d_in[5];
  const void* bk = d_in[6];
  const void* Wv = d_in[7];
  const void* bv = d_in[8];
  const void* Wqc = d_in[9];
  const void* bqc = d_in[10];
  const void* Wkc = d_in[11];
  const void* bkc = d_in[12];
  const void* Wvc = d_in[13];
  const void* bvc = d_in[14];
  const void* Wd = d_in[15];
  const void* bd = d_in[16];
  const void* Wo = d_in[17];
  const void* bo = d_in[18];

  char* ws = (char*)d_ws;
  size_t off = 0;
  auto alloc = [&](size_t bytes) {
    char* p = ws + off;
    off += (bytes + 255) & ~(size_t)255;
    return p;
  };
  int* flag = (int*)alloc(256);
  bf16* small = (bf16*)alloc((size_t)SM_TOT * 2);
  bf16* wctG = (bf16*)alloc((size_t)12288 * 2);
  bf16* wdtG = (bf16*)alloc((size_t)4096 * 2);
  bf16* xb = (bf16*)alloc((size_t)4096 * 2048 * 2);
  bf16* WtQKV = (bf16*)alloc((size_t)6144 * 2048 * 2);
  bf16* WtO = (bf16*)alloc((size_t)2048 * 2048 * 2);
  bf16* qcW = (bf16*)alloc((size_t)65536 * 32 * 2);
  bf16* kcW = (bf16*)alloc((size_t)65536 * 32 * 2);
  bf16* vcTW = (bf16*)alloc((size_t)65536 * 32 * 2);
  bf16* yW = (bf16*)alloc((size_t)4096 * 2048 * 2);

  dim3 tb(256);
  detect_dtype<<<1, 64, 0, stream>>>((const ushort*)x, flag);
  prep<<<160, tb, 0, stream>>>(cosS, sinS, Wqc, Wkc, Wvc, bqc, bkc, bvc, Wd, bd, bo, bq,
                               bk, bv, small, wctG, wdtG, flag);
  transpose4<<<dim3(32, 32, 4), tb, 0, stream>>>(Wq, Wk, Wv, Wo, WtQKV, WtO, flag);
  conv_x<<<4096, tb, 0, stream>>>(x, xb, flag);
  gemm_qkv_compress<<<dim3(48, 32), tb, 0, stream>>>(xb, WtQKV, small, wctG, qcW, kcW,
                                                     vcTW);
  flash32<<<1024, tb, 0, stream>>>(qcW, kcW, vcTW, small, wdtG, yW);
  gemm_bias_out<<<dim3(16, 32), tb, 0, stream>>>(yW, WtO, small + SM_BO, d_out, 4096, 2048,
                                                 2048, flag);
}